// Round 9
// baseline (111.910 us; speedup 1.0000x reference)
//
#include <hip/hip_runtime.h>
#include <hip/hip_bf16.h>
#include <stdint.h>

typedef short bf16x8 __attribute__((ext_vector_type(8)));
typedef float f32x16 __attribute__((ext_vector_type(16)));

static __device__ __forceinline__ short f2bf(float f) {
    __hip_bfloat16 b = __float2bfloat16(f);
    return __builtin_bit_cast(short, b);
}

// ---------------------------------------------------------------------------
// Kernel 1: weights -> bf16 in exact MFMA-fragment order.
// Slot index (one 16B slot per thread):
//   gid = ((((nblk*16 + jt*2 + wn)*3 + g)*16 + ks)*4 + ksub)*64 + lane
// Fragment semantics (mfma_f32_32x32x16_bf16 B operand):
//   j  = jt*64 + wn*32 + (lane&31)
//   kk = ks*64 + ksub*16 + (lane>>5)*8 + t,  t = 0..7
//   kk < 512 -> W_ih[nblk][g*512+j][kk], else W_hh[nblk][g*512+j][kk-512]
// ---------------------------------------------------------------------------
__global__ __launch_bounds__(256) void wconv_kernel(const float* __restrict__ Wih,
                                                    const float* __restrict__ Whh,
                                                    short* __restrict__ Wfrag) {
    const int gid = blockIdx.x * 256 + threadIdx.x;   // 1,572,864 threads
    const int lane = gid & 63;
    const int ksub = (gid >> 6) & 3;
    const int ks   = (gid >> 8) & 15;
    int s = gid >> 12;                                // 0..383
    const int g = s % 3; s /= 3;                      // 0..127
    const int wn = s & 1;
    const int jt = (s >> 1) & 7;
    const int nblk = s >> 4;
    const int j = jt * 64 + wn * 32 + (lane & 31);
    const int kk = ks * 64 + ksub * 16 + (lane >> 5) * 8;
    const float* src = (kk < 512)
        ? Wih + ((int64_t)nblk * 786432 + (int64_t)(g * 512 + j) * 512 + kk)
        : Whh + ((int64_t)nblk * 786432 + (int64_t)(g * 512 + j) * 512 + (kk - 512));
    const float4 a = ((const float4*)src)[0];
    const float4 b = ((const float4*)src)[1];
    bf16x8 o;
    o[0] = f2bf(a.x); o[1] = f2bf(a.y); o[2] = f2bf(a.z); o[3] = f2bf(a.w);
    o[4] = f2bf(b.x); o[5] = f2bf(b.y); o[6] = f2bf(b.z); o[7] = f2bf(b.w);
    *(bf16x8*)(Wfrag + (size_t)gid * 8) = o;
}

// ---------------------------------------------------------------------------
// Kernel 2: fused block-diagonal GRU — LDS-FREE.
// BM=128 x BN=64(x3 gates), 256 thr = 4 waves (2m x 2n), wave tile 64x32,
// m_rep=2, mfma_f32_32x32x16_bf16, acc = 8 x f32x16 = 128 AGPRs.
// B-fragments: coalesced b128 loads from fragment-ordered Wfrag (L2-resident,
// XCD-pinned). A-fragments: 8 consecutive fp32 per lane from x/h + inline
// f2bf. No LDS, no barriers; latency hidden by compiler pipelining + TLP.
// ---------------------------------------------------------------------------
__global__ __launch_bounds__(256, 2) void gru_kernel(
    const float* __restrict__ x, const float* __restrict__ hst,
    const short* __restrict__ Wfrag,
    const float* __restrict__ b_ih, const float* __restrict__ b_hh,
    float* __restrict__ out)
{
    const int tid = threadIdx.x;
    const int nblk = blockIdx.x & 7;          // XCD-local weight slice
    const int rr_ = blockIdx.x >> 3;          // 0..63
    const int bt = rr_ >> 3;                  // batch tile (slow)
    const int jt = rr_ & 7;                   // j tile (fast -> A L2 reuse)
    const int brow0 = bt * 128;

    const int lane = tid & 63;
    const int wave = tid >> 6;                // 0..3
    const int wm = wave >> 1;                 // 0..1 (64-row slice)
    const int wn = wave & 1;                  // 0..1 (32-col slice)
    const int l31 = lane & 31;
    const int k8 = lane >> 5;

    const int arow0 = brow0 + wm * 64 + l31;
    const int arow1 = arow0 + 32;
    const float* xr0 = x + (size_t)arow0 * 4096 + nblk * 512;
    const float* xr1 = x + (size_t)arow1 * 4096 + nblk * 512;
    const float* hr0 = hst + (size_t)arow0 * 4096 + nblk * 512;
    const float* hr1 = hst + (size_t)arow1 * 4096 + nblk * 512;

    // fragment base for this (nblk, jt, wn): per-gate stride 64 KB
    const char* wbase = (const char*)Wfrag
        + ((size_t)(nblk * 16 + jt * 2 + wn) * 3 << 16) + (size_t)lane * 16;

    f32x16 acc_r[2] = {};
    f32x16 acc_z[2] = {};
    f32x16 acc_nx[2] = {};
    f32x16 acc_nh[2] = {};

    auto phase = [&](const float* r0, const float* r1, int ksbase, f32x16 (&accN)[2]) {
        #pragma unroll 2
        for (int ks = 0; ks < 8; ++ks) {
            const float* p0 = r0 + ks * 64;
            const float* p1 = r1 + ks * 64;
            const char* wk = wbase + (size_t)(ksbase + ks) * 4096;
            #pragma unroll
            for (int ksub = 0; ksub < 4; ++ksub) {
                const int co = (ksub * 2 + k8) * 8;
                const float4 a00 = *(const float4*)(p0 + co);
                const float4 a01 = *(const float4*)(p0 + co + 4);
                const float4 a10 = *(const float4*)(p1 + co);
                const float4 a11 = *(const float4*)(p1 + co + 4);
                bf16x8 af0, af1;
                af0[0] = f2bf(a00.x); af0[1] = f2bf(a00.y); af0[2] = f2bf(a00.z); af0[3] = f2bf(a00.w);
                af0[4] = f2bf(a01.x); af0[5] = f2bf(a01.y); af0[6] = f2bf(a01.z); af0[7] = f2bf(a01.w);
                af1[0] = f2bf(a10.x); af1[1] = f2bf(a10.y); af1[2] = f2bf(a10.z); af1[3] = f2bf(a10.w);
                af1[4] = f2bf(a11.x); af1[5] = f2bf(a11.y); af1[6] = f2bf(a11.z); af1[7] = f2bf(a11.w);
                const bf16x8 b0 = *(const bf16x8*)(wk + ksub * 1024 + 0 * 65536);
                const bf16x8 b1 = *(const bf16x8*)(wk + ksub * 1024 + 1 * 65536);
                const bf16x8 b2 = *(const bf16x8*)(wk + ksub * 1024 + 2 * 65536);
                acc_r[0] = __builtin_amdgcn_mfma_f32_32x32x16_bf16(af0, b0, acc_r[0], 0, 0, 0);
                acc_r[1] = __builtin_amdgcn_mfma_f32_32x32x16_bf16(af1, b0, acc_r[1], 0, 0, 0);
                acc_z[0] = __builtin_amdgcn_mfma_f32_32x32x16_bf16(af0, b1, acc_z[0], 0, 0, 0);
                acc_z[1] = __builtin_amdgcn_mfma_f32_32x32x16_bf16(af1, b1, acc_z[1], 0, 0, 0);
                accN[0]  = __builtin_amdgcn_mfma_f32_32x32x16_bf16(af0, b2, accN[0], 0, 0, 0);
                accN[1]  = __builtin_amdgcn_mfma_f32_32x32x16_bf16(af1, b2, accN[1], 0, 0, 0);
            }
        }
    };

    phase(xr0, xr1, 0, acc_nx);   // k 0..511   (W_ih half)
    phase(hr0, hr1, 8, acc_nh);   // k 512..1023 (W_hh half)

    // ---- epilogue: gates + output (wave owns 64x32 tile) ----
    const int jb = jt * 64 + wn * 32 + l31;   // [0,512)
    const int bb = nblk * 1536 + jb;
    const float br = b_ih[bb] + b_hh[bb];
    const float bz = b_ih[bb + 512] + b_hh[bb + 512];
    const float bnx = b_ih[bb + 1024];
    const float bnh = b_hh[bb + 1024];
    const int gcol = nblk * 512 + jb;
    #pragma unroll
    for (int m = 0; m < 2; ++m) {
        #pragma unroll
        for (int rr = 0; rr < 16; ++rr) {
            const int rowl = (rr & 3) + 8 * (rr >> 2) + 4 * k8;
            const int row = brow0 + wm * 64 + m * 32 + rowl;
            const size_t idx = (size_t)row * 4096 + gcol;
            const float sr = acc_r[m][rr] + br;
            const float sz = acc_z[m][rr] + bz;
            const float rg = 1.f / (1.f + __expf(-sr));
            const float zg = 1.f / (1.f + __expf(-sz));
            const float tin = (acc_nx[m][rr] + bnx) + rg * (acc_nh[m][rr] + bnh);
            const float e2 = __expf(-2.f * tin);
            const float ng = 2.f / (1.f + e2) - 1.f;
            const float hv = hst[idx];
            out[idx] = ng + zg * (hv - ng);
        }
    }
}

extern "C" void kernel_launch(void* const* d_in, const int* in_sizes, int n_in,
                              void* d_out, int out_size, void* d_ws, size_t ws_size,
                              hipStream_t stream) {
    (void)in_sizes; (void)n_in; (void)out_size; (void)ws_size;
    const float* x    = (const float*)d_in[0];
    const float* h    = (const float*)d_in[1];
    const float* W_ih = (const float*)d_in[2];
    const float* W_hh = (const float*)d_in[3];
    const float* b_ih = (const float*)d_in[4];
    const float* b_hh = (const float*)d_in[5];
    short* Wfrag = (short*)d_ws;              // 24 MB, fragment-ordered bf16

    wconv_kernel<<<6144, 256, 0, stream>>>(W_ih, W_hh, Wfrag);
    gru_kernel<<<512, 256, 0, stream>>>(x, h, Wfrag, b_ih, b_hh, (float*)d_out);
}

// Round 10
// 84.643 us; speedup vs baseline: 1.3221x; 1.3221x over previous
//
#include <hip/hip_runtime.h>
#include <hip/hip_bf16.h>
#include <stdint.h>

typedef short bf16x8 __attribute__((ext_vector_type(8)));
typedef float f32x16 __attribute__((ext_vector_type(16)));

static __device__ __forceinline__ short f2bf(float f) {
    __hip_bfloat16 b = __float2bfloat16(f);
    return __builtin_bit_cast(short, b);
}

// ---------------------------------------------------------------------------
// Kernel 1: weights -> bf16 in exact MFMA-fragment order (same as R8).
// Slot gid = ((((nblk*16 + jt*2 + wn)*3 + g)*16 + ks)*4 + ksub)*64 + lane
//   j  = jt*64 + wn*32 + (lane&31)
//   kk = ks*64 + ksub*16 + (lane>>5)*8 + t, t=0..7
//   kk < 512 -> W_ih[nblk][g*512+j][kk], else W_hh[nblk][g*512+j][kk-512]
// ---------------------------------------------------------------------------
__global__ __launch_bounds__(256) void wconv_kernel(const float* __restrict__ Wih,
                                                    const float* __restrict__ Whh,
                                                    short* __restrict__ Wfrag) {
    const int gid = blockIdx.x * 256 + threadIdx.x;   // 1,572,864 threads
    const int lane = gid & 63;
    const int ksub = (gid >> 6) & 3;
    const int ks   = (gid >> 8) & 15;
    int s = gid >> 12;                                // 0..383
    const int g = s % 3; s /= 3;
    const int wn = s & 1;
    const int jt = (s >> 1) & 7;
    const int nblk = s >> 4;
    const int j = jt * 64 + wn * 32 + (lane & 31);
    const int kk = ks * 64 + ksub * 16 + (lane >> 5) * 8;
    const float* src = (kk < 512)
        ? Wih + ((int64_t)nblk * 786432 + (int64_t)(g * 512 + j) * 512 + kk)
        : Whh + ((int64_t)nblk * 786432 + (int64_t)(g * 512 + j) * 512 + (kk - 512));
    const float4 a = ((const float4*)src)[0];
    const float4 b = ((const float4*)src)[1];
    bf16x8 o;
    o[0] = f2bf(a.x); o[1] = f2bf(a.y); o[2] = f2bf(a.z); o[3] = f2bf(a.w);
    o[4] = f2bf(b.x); o[5] = f2bf(b.y); o[6] = f2bf(b.z); o[7] = f2bf(b.w);
    *(bf16x8*)(Wfrag + (size_t)gid * 8) = o;
}

// ---------------------------------------------------------------------------
// Kernel 1b: x,h -> bf16 A-fragment image.
// Axh[row 0..1023][nblk 0..7][kk 0..1023], kk<512 = x, kk>=512 = h.
// Lane A-fragment for step s is the 16B at kk = s*8 + (lane>>5)*8... laid out
// so a lane reads Axh[(row*8+nblk)*1024 + s*16 + k8*8] as bf16x8.
// ---------------------------------------------------------------------------
__global__ __launch_bounds__(256) void aconv_kernel(const float* __restrict__ x,
                                                    const float* __restrict__ h,
                                                    short* __restrict__ Axh) {
    const int gid = blockIdx.x * 256 + threadIdx.x;   // 1,048,576 threads
    const int64_t e = (int64_t)gid * 8;
    const int kk = (int)(e & 1023);
    const int nblk = (int)((e >> 10) & 7);
    const int row = (int)(e >> 13);
    const float* src = (kk < 512)
        ? x + ((size_t)row * 4096 + nblk * 512 + kk)
        : h + ((size_t)row * 4096 + nblk * 512 + (kk - 512));
    const float4 a = ((const float4*)src)[0];
    const float4 b = ((const float4*)src)[1];
    bf16x8 o;
    o[0] = f2bf(a.x); o[1] = f2bf(a.y); o[2] = f2bf(a.z); o[3] = f2bf(a.w);
    o[4] = f2bf(b.x); o[5] = f2bf(b.y); o[6] = f2bf(b.z); o[7] = f2bf(b.w);
    *(bf16x8*)(Axh + e) = o;
}

// ---------------------------------------------------------------------------
// Kernel 2: fused block-diagonal GRU — LDS-free, ping-pong prefetch.
// BM=64 x BN=64(x3 gates), 256 thr = 4 waves (2m x 2n), wave tile 32x32,
// acc = 4 x f32x16 = 64 regs. Grid 1024 = 4 blocks/CU = 16 waves/CU.
// Per step: 4 x 16B loads (1 A + 3 B) + 3 MFMA, zero conversion VALU.
// Explicit P/Q register double-buffer: loads for s+1 issued before MFMAs(s).
// ---------------------------------------------------------------------------
__global__ __launch_bounds__(256, 4) void gru_kernel(
    const float* __restrict__ hst,
    const short* __restrict__ Wfrag, const short* __restrict__ Axh,
    const float* __restrict__ b_ih, const float* __restrict__ b_hh,
    float* __restrict__ out)
{
    const int tid = threadIdx.x;
    const int nblk = blockIdx.x & 7;          // XCD-local weight slice
    const int rr_ = blockIdx.x >> 3;          // 0..127
    const int bt = rr_ >> 3;                  // 0..15 batch tile (slow)
    const int jt = rr_ & 7;                   // j tile (fast -> A L2 reuse)
    const int brow0 = bt * 64;

    const int lane = tid & 63;
    const int wave = tid >> 6;                // 0..3
    const int wm = wave >> 1;                 // 0..1 (32-row slice)
    const int wn = wave & 1;                  // 0..1 (32-col slice)
    const int l31 = lane & 31;
    const int k8 = lane >> 5;

    const int arow = brow0 + wm * 32 + l31;
    const char* abase = (const char*)Axh + ((size_t)(arow * 8 + nblk) << 11) + k8 * 16;
    const char* wb = (const char*)Wfrag
        + ((size_t)((nblk * 16 + jt * 2 + wn) * 3) << 16) + (size_t)lane * 16;

    f32x16 acc_r = {};
    f32x16 acc_z = {};
    f32x16 acc_nx = {};
    f32x16 acc_nh = {};

    bf16x8 aP, b0P, b1P, b2P, aQ, b0Q, b1Q, b2Q;

    auto LDP = [&](int s) {
        const int sc = s > 63 ? 63 : s;       // clamp: last prefetch re-reads s=63
        aP  = *(const bf16x8*)(abase + sc * 32);
        b0P = *(const bf16x8*)(wb + (size_t)sc * 1024);
        b1P = *(const bf16x8*)(wb + (size_t)sc * 1024 + 65536);
        b2P = *(const bf16x8*)(wb + (size_t)sc * 1024 + 131072);
    };
    auto LDQ = [&](int s) {
        const int sc = s > 63 ? 63 : s;
        aQ  = *(const bf16x8*)(abase + sc * 32);
        b0Q = *(const bf16x8*)(wb + (size_t)sc * 1024);
        b1Q = *(const bf16x8*)(wb + (size_t)sc * 1024 + 65536);
        b2Q = *(const bf16x8*)(wb + (size_t)sc * 1024 + 131072);
    };

    LDP(0);
    #pragma unroll 1
    for (int i = 0; i < 16; ++i) {            // steps s = 2i, 2i+1  (kk < 512)
        const int s = 2 * i;
        LDQ(s + 1);
        acc_r  = __builtin_amdgcn_mfma_f32_32x32x16_bf16(aP, b0P, acc_r, 0, 0, 0);
        acc_z  = __builtin_amdgcn_mfma_f32_32x32x16_bf16(aP, b1P, acc_z, 0, 0, 0);
        acc_nx = __builtin_amdgcn_mfma_f32_32x32x16_bf16(aP, b2P, acc_nx, 0, 0, 0);
        LDP(s + 2);
        acc_r  = __builtin_amdgcn_mfma_f32_32x32x16_bf16(aQ, b0Q, acc_r, 0, 0, 0);
        acc_z  = __builtin_amdgcn_mfma_f32_32x32x16_bf16(aQ, b1Q, acc_z, 0, 0, 0);
        acc_nx = __builtin_amdgcn_mfma_f32_32x32x16_bf16(aQ, b2Q, acc_nx, 0, 0, 0);
    }
    #pragma unroll 1
    for (int i = 0; i < 16; ++i) {            // steps s = 32..63  (kk >= 512)
        const int s = 32 + 2 * i;
        LDQ(s + 1);
        acc_r  = __builtin_amdgcn_mfma_f32_32x32x16_bf16(aP, b0P, acc_r, 0, 0, 0);
        acc_z  = __builtin_amdgcn_mfma_f32_32x32x16_bf16(aP, b1P, acc_z, 0, 0, 0);
        acc_nh = __builtin_amdgcn_mfma_f32_32x32x16_bf16(aP, b2P, acc_nh, 0, 0, 0);
        LDP(s + 2);
        acc_r  = __builtin_amdgcn_mfma_f32_32x32x16_bf16(aQ, b0Q, acc_r, 0, 0, 0);
        acc_z  = __builtin_amdgcn_mfma_f32_32x32x16_bf16(aQ, b1Q, acc_z, 0, 0, 0);
        acc_nh = __builtin_amdgcn_mfma_f32_32x32x16_bf16(aQ, b2Q, acc_nh, 0, 0, 0);
    }

    // ---- epilogue: gates + output (wave owns 32x32 tile) ----
    const int jb = jt * 64 + wn * 32 + l31;   // [0,512)
    const int bb = nblk * 1536 + jb;
    const float br = b_ih[bb] + b_hh[bb];
    const float bz = b_ih[bb + 512] + b_hh[bb + 512];
    const float bnx = b_ih[bb + 1024];
    const float bnh = b_hh[bb + 1024];
    const int gcol = nblk * 512 + jb;
    #pragma unroll
    for (int rr = 0; rr < 16; ++rr) {
        const int rowl = (rr & 3) + 8 * (rr >> 2) + 4 * k8;
        const int row = brow0 + wm * 32 + rowl;
        const size_t idx = (size_t)row * 4096 + gcol;
        const float sr = acc_r[rr] + br;
        const float sz = acc_z[rr] + bz;
        const float rg = 1.f / (1.f + __expf(-sr));
        const float zg = 1.f / (1.f + __expf(-sz));
        const float tin = (acc_nx[rr] + bnx) + rg * (acc_nh[rr] + bnh);
        const float e2 = __expf(-2.f * tin);
        const float ng = 2.f / (1.f + e2) - 1.f;
        const float hv = hst[idx];
        out[idx] = ng + zg * (hv - ng);
    }
}

extern "C" void kernel_launch(void* const* d_in, const int* in_sizes, int n_in,
                              void* d_out, int out_size, void* d_ws, size_t ws_size,
                              hipStream_t stream) {
    (void)in_sizes; (void)n_in; (void)out_size; (void)ws_size;
    const float* x    = (const float*)d_in[0];
    const float* h    = (const float*)d_in[1];
    const float* W_ih = (const float*)d_in[2];
    const float* W_hh = (const float*)d_in[3];
    const float* b_ih = (const float*)d_in[4];
    const float* b_hh = (const float*)d_in[5];
    short* Wfrag = (short*)d_ws;                              // 24 MB
    short* Axh   = (short*)d_ws + (size_t)12 * 1024 * 1024;   // 16 MB

    wconv_kernel<<<6144, 256, 0, stream>>>(W_ih, W_hh, Wfrag);
    aconv_kernel<<<4096, 256, 0, stream>>>(x, h, Axh);
    gru_kernel<<<1024, 256, 0, stream>>>(h, Wfrag, Axh, b_ih, b_hh, (float*)d_out);
}

// Round 11
// 75.740 us; speedup vs baseline: 1.4776x; 1.1175x over previous
//
#include <hip/hip_runtime.h>
#include <hip/hip_bf16.h>
#include <stdint.h>

typedef short bf16x8 __attribute__((ext_vector_type(8)));
typedef float f32x16 __attribute__((ext_vector_type(16)));

static __device__ __forceinline__ short f2bf(float f) {
    __hip_bfloat16 b = __float2bfloat16(f);
    return __builtin_bit_cast(short, b);
}

// ---------------------------------------------------------------------------
// Kernel 1: weights -> bf16 in exact MFMA-fragment order.
// Slot gid = ((((nblk*16 + jt*2 + wn)*3 + g)*16 + ks)*4 + ksub)*64 + lane
//   j  = jt*64 + wn*32 + (lane&31)
//   kk = ks*64 + ksub*16 + (lane>>5)*8 + t, t=0..7
//   kk < 512 -> W_ih[nblk][g*512+j][kk], else W_hh[nblk][g*512+j][kk-512]
// ---------------------------------------------------------------------------
__global__ __launch_bounds__(256) void wconv_kernel(const float* __restrict__ Wih,
                                                    const float* __restrict__ Whh,
                                                    short* __restrict__ Wfrag) {
    const int gid = blockIdx.x * 256 + threadIdx.x;   // 1,572,864 threads
    const int lane = gid & 63;
    const int ksub = (gid >> 6) & 3;
    const int ks   = (gid >> 8) & 15;
    int s = gid >> 12;                                // 0..383
    const int g = s % 3; s /= 3;
    const int wn = s & 1;
    const int jt = (s >> 1) & 7;
    const int nblk = s >> 4;
    const int j = jt * 64 + wn * 32 + (lane & 31);
    const int kk = ks * 64 + ksub * 16 + (lane >> 5) * 8;
    const float* src = (kk < 512)
        ? Wih + ((int64_t)nblk * 786432 + (int64_t)(g * 512 + j) * 512 + kk)
        : Whh + ((int64_t)nblk * 786432 + (int64_t)(g * 512 + j) * 512 + (kk - 512));
    const float4 a = ((const float4*)src)[0];
    const float4 b = ((const float4*)src)[1];
    bf16x8 o;
    o[0] = f2bf(a.x); o[1] = f2bf(a.y); o[2] = f2bf(a.z); o[3] = f2bf(a.w);
    o[4] = f2bf(b.x); o[5] = f2bf(b.y); o[6] = f2bf(b.z); o[7] = f2bf(b.w);
    *(bf16x8*)(Wfrag + (size_t)gid * 8) = o;
}

// ---------------------------------------------------------------------------
// Kernel 1b: x,h -> bf16 A-fragment image.
// Axh[row 0..1023][nblk 0..7][kk 0..1023], kk<512 = x, kk>=512 = h.
// ---------------------------------------------------------------------------
__global__ __launch_bounds__(256) void aconv_kernel(const float* __restrict__ x,
                                                    const float* __restrict__ h,
                                                    short* __restrict__ Axh) {
    const int gid = blockIdx.x * 256 + threadIdx.x;   // 1,048,576 threads
    const int64_t e = (int64_t)gid * 8;
    const int kk = (int)(e & 1023);
    const int nblk = (int)((e >> 10) & 7);
    const int row = (int)(e >> 13);
    const float* src = (kk < 512)
        ? x + ((size_t)row * 4096 + nblk * 512 + kk)
        : h + ((size_t)row * 4096 + nblk * 512 + (kk - 512));
    const float4 a = ((const float4*)src)[0];
    const float4 b = ((const float4*)src)[1];
    bf16x8 o;
    o[0] = f2bf(a.x); o[1] = f2bf(a.y); o[2] = f2bf(a.z); o[3] = f2bf(a.w);
    o[4] = f2bf(b.x); o[5] = f2bf(b.y); o[6] = f2bf(b.z); o[7] = f2bf(b.w);
    *(bf16x8*)(Axh + e) = o;
}

// ---------------------------------------------------------------------------
// Kernel 2: fused block-diagonal GRU — LDS-free, depth-2 register prefetch.
// BM=256 x BN=64(x3 gates), 512 thr = 8 waves (4m x 2n), wave tile 64x32
// (m_rep=2), acc = 8 x f32x16 = 128 AGPRs. Grid 256 = 1 block/CU.
// Per step: 5 x 16B L2 loads (2 A + 3 B) + 6 MFMA. No LDS, no barriers.
// 4 named fragment sets (P,Q,R,S), static rotation, prefetch distance 2.
// ---------------------------------------------------------------------------
__global__ __launch_bounds__(512, 2) void gru_kernel(
    const float* __restrict__ hst,
    const short* __restrict__ Wfrag, const short* __restrict__ Axh,
    const float* __restrict__ b_ih, const float* __restrict__ b_hh,
    float* __restrict__ out)
{
    const int tid = threadIdx.x;
    const int nblk = blockIdx.x & 7;          // XCD-local weight slice
    const int rr_ = blockIdx.x >> 3;          // 0..31
    const int bt = rr_ >> 3;                  // 0..3 batch tile (slow)
    const int jt = rr_ & 7;                   // j tile (fast -> A L2 reuse)
    const int brow0 = bt * 256;

    const int lane = tid & 63;
    const int wave = tid >> 6;                // 0..7
    const int wm = wave >> 1;                 // 0..3 (64-row slice)
    const int wn = wave & 1;                  // 0..1 (32-col slice)
    const int l31 = lane & 31;
    const int k8 = lane >> 5;

    const int arow0 = brow0 + wm * 64 + l31;
    const int arow1 = arow0 + 32;
    const char* ab0 = (const char*)Axh + ((size_t)(arow0 * 8 + nblk) << 11) + k8 * 16;
    const char* ab1 = (const char*)Axh + ((size_t)(arow1 * 8 + nblk) << 11) + k8 * 16;
    const char* wb = (const char*)Wfrag
        + ((size_t)((nblk * 16 + jt * 2 + wn) * 3) << 16) + (size_t)lane * 16;

    f32x16 acc_r[2] = {};
    f32x16 acc_z[2] = {};
    f32x16 acc_nx[2] = {};
    f32x16 acc_nh[2] = {};

    bf16x8 a0P, a1P, b0P, b1P, b2P;
    bf16x8 a0Q, a1Q, b0Q, b1Q, b2Q;
    bf16x8 a0R, a1R, b0R, b1R, b2R;
    bf16x8 a0S, a1S, b0S, b1S, b2S;

#define LDSET(T, s_)                                                       \
    {                                                                      \
        const int sc = (s_) > 63 ? 63 : (s_);                              \
        a0##T = *(const bf16x8*)(ab0 + sc * 32);                           \
        a1##T = *(const bf16x8*)(ab1 + sc * 32);                           \
        b0##T = *(const bf16x8*)(wb + (size_t)sc * 1024);                  \
        b1##T = *(const bf16x8*)(wb + (size_t)sc * 1024 + 65536);          \
        b2##T = *(const bf16x8*)(wb + (size_t)sc * 1024 + 131072);         \
    }

#define FMSET(T, accN)                                                             \
    {                                                                              \
        acc_r[0] = __builtin_amdgcn_mfma_f32_32x32x16_bf16(a0##T, b0##T, acc_r[0], 0, 0, 0); \
        acc_r[1] = __builtin_amdgcn_mfma_f32_32x32x16_bf16(a1##T, b0##T, acc_r[1], 0, 0, 0); \
        acc_z[0] = __builtin_amdgcn_mfma_f32_32x32x16_bf16(a0##T, b1##T, acc_z[0], 0, 0, 0); \
        acc_z[1] = __builtin_amdgcn_mfma_f32_32x32x16_bf16(a1##T, b1##T, acc_z[1], 0, 0, 0); \
        accN[0]  = __builtin_amdgcn_mfma_f32_32x32x16_bf16(a0##T, b2##T, accN[0], 0, 0, 0);  \
        accN[1]  = __builtin_amdgcn_mfma_f32_32x32x16_bf16(a1##T, b2##T, accN[1], 0, 0, 0);  \
    }

    LDSET(P, 0)
    LDSET(Q, 1)

    #pragma unroll 1
    for (int grp = 0; grp < 8; ++grp) {       // steps 0..31 (kk < 512) -> acc_nx
        const int s = grp * 4;
        LDSET(R, s + 2) FMSET(P, acc_nx)
        LDSET(S, s + 3) FMSET(Q, acc_nx)
        LDSET(P, s + 4) FMSET(R, acc_nx)
        LDSET(Q, s + 5) FMSET(S, acc_nx)
    }
    #pragma unroll 1
    for (int grp = 8; grp < 16; ++grp) {      // steps 32..63 (kk >= 512) -> acc_nh
        const int s = grp * 4;
        LDSET(R, s + 2) FMSET(P, acc_nh)
        LDSET(S, s + 3) FMSET(Q, acc_nh)
        LDSET(P, s + 4) FMSET(R, acc_nh)
        LDSET(Q, s + 5) FMSET(S, acc_nh)
    }
#undef LDSET
#undef FMSET

    // ---- epilogue: gates + output (wave owns 64x32 tile) ----
    const int jb = jt * 64 + wn * 32 + l31;   // [0,512)
    const int bb = nblk * 1536 + jb;
    const float br = b_ih[bb] + b_hh[bb];
    const float bz = b_ih[bb + 512] + b_hh[bb + 512];
    const float bnx = b_ih[bb + 1024];
    const float bnh = b_hh[bb + 1024];
    const int gcol = nblk * 512 + jb;
    #pragma unroll
    for (int m = 0; m < 2; ++m) {
        #pragma unroll
        for (int rr = 0; rr < 16; ++rr) {
            const int rowl = (rr & 3) + 8 * (rr >> 2) + 4 * k8;
            const int row = brow0 + wm * 64 + m * 32 + rowl;
            const size_t idx = (size_t)row * 4096 + gcol;
            const float sr = acc_r[m][rr] + br;
            const float sz = acc_z[m][rr] + bz;
            const float rg = 1.f / (1.f + __expf(-sr));
            const float zg = 1.f / (1.f + __expf(-sz));
            const float tin = (acc_nx[m][rr] + bnx) + rg * (acc_nh[m][rr] + bnh);
            const float e2 = __expf(-2.f * tin);
            const float ng = 2.f / (1.f + e2) - 1.f;
            const float hv = hst[idx];
            out[idx] = ng + zg * (hv - ng);
        }
    }
}

extern "C" void kernel_launch(void* const* d_in, const int* in_sizes, int n_in,
                              void* d_out, int out_size, void* d_ws, size_t ws_size,
                              hipStream_t stream) {
    (void)in_sizes; (void)n_in; (void)out_size; (void)ws_size;
    const float* x    = (const float*)d_in[0];
    const float* h    = (const float*)d_in[1];
    const float* W_ih = (const float*)d_in[2];
    const float* W_hh = (const float*)d_in[3];
    const float* b_ih = (const float*)d_in[4];
    const float* b_hh = (const float*)d_in[5];
    short* Wfrag = (short*)d_ws;                              // 24 MB
    short* Axh   = (short*)d_ws + (size_t)12 * 1024 * 1024;   // 16 MB

    wconv_kernel<<<6144, 256, 0, stream>>>(W_ih, W_hh, Wfrag);
    aconv_kernel<<<4096, 256, 0, stream>>>(x, h, Axh);
    gru_kernel<<<256, 512, 0, stream>>>(h, Wfrag, Axh, b_ih, b_hh, (float*)d_out);
}

// Round 12
// 59.025 us; speedup vs baseline: 1.8960x; 1.2832x over previous
//
#include <hip/hip_runtime.h>
#include <hip/hip_bf16.h>
#include <stdint.h>

typedef short bf16x8 __attribute__((ext_vector_type(8)));
typedef float f32x16 __attribute__((ext_vector_type(16)));

static __device__ __forceinline__ short f2bf(float f) {
    __hip_bfloat16 b = __float2bfloat16(f);
    return __builtin_bit_cast(short, b);
}

// ---------------------------------------------------------------------------
// Kernel 1: weights -> bf16 in exact MFMA-fragment order.
// gid = ((((nblk*16 + jt*2 + wn)*3 + g)*16 + ks)*4 + ksub)*64 + lane
//   j  = jt*64 + wn*32 + (lane&31)
//   kk = ks*64 + ksub*16 + (lane>>5)*8 + t, t=0..7
//   kk < 512 -> W_ih[nblk][g*512+j][kk], else W_hh[nblk][g*512+j][kk-512]
// Block index permuted so writer XCD (b%8) == consumer XCD (nblk).
// ---------------------------------------------------------------------------
__global__ __launch_bounds__(256) void wconv_kernel(const float* __restrict__ Wih,
                                                    const float* __restrict__ Whh,
                                                    short* __restrict__ Wfrag) {
    const int b = blockIdx.x;                         // 6144
    const int vb = (b & 7) * 768 + (b >> 3);          // XCD-aligned permute
    const int gid = vb * 256 + threadIdx.x;
    const int lane = gid & 63;
    const int ksub = (gid >> 6) & 3;
    const int ks   = (gid >> 8) & 15;
    int s = gid >> 12;                                // 0..383
    const int g = s % 3; s /= 3;
    const int wn = s & 1;
    const int jt = (s >> 1) & 7;
    const int nblk = s >> 4;
    const int j = jt * 64 + wn * 32 + (lane & 31);
    const int kk = ks * 64 + ksub * 16 + (lane >> 5) * 8;
    const float* src = (kk < 512)
        ? Wih + ((int64_t)nblk * 786432 + (int64_t)(g * 512 + j) * 512 + kk)
        : Whh + ((int64_t)nblk * 786432 + (int64_t)(g * 512 + j) * 512 + (kk - 512));
    const float4 a = ((const float4*)src)[0];
    const float4 bq = ((const float4*)src)[1];
    bf16x8 o;
    o[0] = f2bf(a.x); o[1] = f2bf(a.y); o[2] = f2bf(a.z); o[3] = f2bf(a.w);
    o[4] = f2bf(bq.x); o[5] = f2bf(bq.y); o[6] = f2bf(bq.z); o[7] = f2bf(bq.w);
    *(bf16x8*)(Wfrag + (size_t)gid * 8) = o;
}

// ---------------------------------------------------------------------------
// Kernel 1b: x,h -> bf16 A-image in MFMA fragment order (gather style).
// Afrag[rb 0..31][nblk 0..7][s 0..63][lane 0..63][8 bf16]:
//   row = rb*32 + (lane&31),  kk = s*16 + (lane>>5)*8   (kk<512 = x, else h)
// Writes perfectly coalesced; block mapping XCD-aligned (b%8 == nblk).
// ---------------------------------------------------------------------------
__global__ __launch_bounds__(256) void aconv_kernel(const float* __restrict__ x,
                                                    const float* __restrict__ h,
                                                    short* __restrict__ Afrag) {
    const int b = blockIdx.x;                 // 4096
    const int n = b & 7;                      // == consumer XCD
    const int inner = b >> 3;                 // 0..511
    const int rb = inner >> 4;                // 0..31
    const int u = inner & 15;                 // 0..15
    const int tid = threadIdx.x;
    const int lane = tid & 63;
    const int s = u * 4 + (tid >> 6);         // 0..63
    const int row = rb * 32 + (lane & 31);
    const int kk = s * 16 + (lane >> 5) * 8;  // 0..1023
    const float* src = (kk < 512)
        ? x + ((size_t)row * 4096 + n * 512 + kk)
        : h + ((size_t)row * 4096 + n * 512 + (kk - 512));
    const float4 a = ((const float4*)src)[0];
    const float4 bq = ((const float4*)src)[1];
    bf16x8 o;
    o[0] = f2bf(a.x); o[1] = f2bf(a.y); o[2] = f2bf(a.z); o[3] = f2bf(a.w);
    o[4] = f2bf(bq.x); o[5] = f2bf(bq.y); o[6] = f2bf(bq.z); o[7] = f2bf(bq.w);
    const size_t dst = ((((size_t)(rb * 8 + n) * 64 + s) * 64) + lane) * 8;
    *(bf16x8*)(Afrag + dst) = o;
}

// ---------------------------------------------------------------------------
// Kernel 2: fused block-diagonal GRU — LDS-free, depth-2 register prefetch.
// BM=256 x BN=64(x3 gates), 512 thr = 8 waves (4m x 2n), wave tile 64x32
// (m_rep=2), acc = 8 x f32x16 = 128 AGPRs. Grid 256 = 1 block/CU.
// Per step: 5 coalesced 1KB wave-loads (2 A + 3 B) + 6 MFMA. No LDS/barriers.
// 4 named fragment sets (P,Q,R,S), static rotation, prefetch distance 2.
// ---------------------------------------------------------------------------
__global__ __launch_bounds__(512, 2) void gru_kernel(
    const float* __restrict__ hst,
    const short* __restrict__ Wfrag, const short* __restrict__ Afrag,
    const float* __restrict__ b_ih, const float* __restrict__ b_hh,
    float* __restrict__ out)
{
    const int tid = threadIdx.x;
    const int nblk = blockIdx.x & 7;          // XCD-local weight slice
    const int rr_ = blockIdx.x >> 3;          // 0..31
    const int bt = rr_ >> 3;                  // 0..3 batch tile (slow)
    const int jt = rr_ & 7;                   // j tile (fast -> A L2 reuse)
    const int brow0 = bt * 256;

    const int lane = tid & 63;
    const int wave = tid >> 6;                // 0..7
    const int wm = wave >> 1;                 // 0..3 (64-row slice)
    const int wn = wave & 1;                  // 0..1 (32-col slice)
    const int l31 = lane & 31;
    const int k8 = lane >> 5;

    // A fragment bases: rb0 = 32-row tile of rows [brow0+wm*64, +32)
    const int rb0 = (brow0 + wm * 64) >> 5;
    const char* ab0 = (const char*)Afrag + ((size_t)(rb0 * 8 + nblk) << 16) + (size_t)lane * 16;
    const char* ab1 = ab0 + (8 << 16);        // rb0 + 1
    const char* wb = (const char*)Wfrag
        + ((size_t)((nblk * 16 + jt * 2 + wn) * 3) << 16) + (size_t)lane * 16;

    f32x16 acc_r[2] = {};
    f32x16 acc_z[2] = {};
    f32x16 acc_nx[2] = {};
    f32x16 acc_nh[2] = {};

    bf16x8 a0P, a1P, b0P, b1P, b2P;
    bf16x8 a0Q, a1Q, b0Q, b1Q, b2Q;
    bf16x8 a0R, a1R, b0R, b1R, b2R;
    bf16x8 a0S, a1S, b0S, b1S, b2S;

#define LDSET(T, s_)                                                       \
    {                                                                      \
        const int sc = (s_) > 63 ? 63 : (s_);                              \
        a0##T = *(const bf16x8*)(ab0 + (size_t)sc * 1024);                 \
        a1##T = *(const bf16x8*)(ab1 + (size_t)sc * 1024);                 \
        b0##T = *(const bf16x8*)(wb + (size_t)sc * 1024);                  \
        b1##T = *(const bf16x8*)(wb + (size_t)sc * 1024 + 65536);          \
        b2##T = *(const bf16x8*)(wb + (size_t)sc * 1024 + 131072);         \
    }

#define FMSET(T, accN)                                                             \
    {                                                                              \
        acc_r[0] = __builtin_amdgcn_mfma_f32_32x32x16_bf16(a0##T, b0##T, acc_r[0], 0, 0, 0); \
        acc_r[1] = __builtin_amdgcn_mfma_f32_32x32x16_bf16(a1##T, b0##T, acc_r[1], 0, 0, 0); \
        acc_z[0] = __builtin_amdgcn_mfma_f32_32x32x16_bf16(a0##T, b1##T, acc_z[0], 0, 0, 0); \
        acc_z[1] = __builtin_amdgcn_mfma_f32_32x32x16_bf16(a1##T, b1##T, acc_z[1], 0, 0, 0); \
        accN[0]  = __builtin_amdgcn_mfma_f32_32x32x16_bf16(a0##T, b2##T, accN[0], 0, 0, 0);  \
        accN[1]  = __builtin_amdgcn_mfma_f32_32x32x16_bf16(a1##T, b2##T, accN[1], 0, 0, 0);  \
    }

    LDSET(P, 0)
    LDSET(Q, 1)

    #pragma unroll 1
    for (int grp = 0; grp < 8; ++grp) {       // steps 0..31 (kk < 512) -> acc_nx
        const int s = grp * 4;
        LDSET(R, s + 2) FMSET(P, acc_nx)
        LDSET(S, s + 3) FMSET(Q, acc_nx)
        LDSET(P, s + 4) FMSET(R, acc_nx)
        LDSET(Q, s + 5) FMSET(S, acc_nx)
    }
    #pragma unroll 1
    for (int grp = 8; grp < 16; ++grp) {      // steps 32..63 (kk >= 512) -> acc_nh
        const int s = grp * 4;
        LDSET(R, s + 2) FMSET(P, acc_nh)
        LDSET(S, s + 3) FMSET(Q, acc_nh)
        LDSET(P, s + 4) FMSET(R, acc_nh)
        LDSET(Q, s + 5) FMSET(S, acc_nh)
    }
#undef LDSET
#undef FMSET

    // ---- epilogue: gates + output (wave owns 64x32 tile) ----
    const int jb = jt * 64 + wn * 32 + l31;   // [0,512)
    const int bb = nblk * 1536 + jb;
    const float br = b_ih[bb] + b_hh[bb];
    const float bz = b_ih[bb + 512] + b_hh[bb + 512];
    const float bnx = b_ih[bb + 1024];
    const float bnh = b_hh[bb + 1024];
    const int gcol = nblk * 512 + jb;
    #pragma unroll
    for (int m = 0; m < 2; ++m) {
        #pragma unroll
        for (int rr = 0; rr < 16; ++rr) {
            const int rowl = (rr & 3) + 8 * (rr >> 2) + 4 * k8;
            const int row = brow0 + wm * 64 + m * 32 + rowl;
            const size_t idx = (size_t)row * 4096 + gcol;
            const float sr = acc_r[m][rr] + br;
            const float sz = acc_z[m][rr] + bz;
            const float rg = 1.f / (1.f + __expf(-sr));
            const float zg = 1.f / (1.f + __expf(-sz));
            const float tin = (acc_nx[m][rr] + bnx) + rg * (acc_nh[m][rr] + bnh);
            const float e2 = __expf(-2.f * tin);
            const float ng = 2.f / (1.f + e2) - 1.f;
            const float hv = hst[idx];
            out[idx] = ng + zg * (hv - ng);
        }
    }
}

extern "C" void kernel_launch(void* const* d_in, const int* in_sizes, int n_in,
                              void* d_out, int out_size, void* d_ws, size_t ws_size,
                              hipStream_t stream) {
    (void)in_sizes; (void)n_in; (void)out_size; (void)ws_size;
    const float* x    = (const float*)d_in[0];
    const float* h    = (const float*)d_in[1];
    const float* W_ih = (const float*)d_in[2];
    const float* W_hh = (const float*)d_in[3];
    const float* b_ih = (const float*)d_in[4];
    const float* b_hh = (const float*)d_in[5];
    short* Wfrag = (short*)d_ws;                              // 24 MB
    short* Afrag = (short*)d_ws + (size_t)12 * 1024 * 1024;   // 16 MB

    wconv_kernel<<<6144, 256, 0, stream>>>(W_ih, W_hh, Wfrag);
    aconv_kernel<<<4096, 256, 0, stream>>>(x, h, Afrag);
    gru_kernel<<<256, 512, 0, stream>>>(h, Wfrag, Afrag, b_ih, b_hh, (float*)d_out);
}